// Round 3
// baseline (107.375 us; speedup 1.0000x reference)
//
#include <hip/hip_runtime.h>
#include <math.h>

#define FEAS 4096
#define K 64
#define BATCH 4096
#define NBLK 64

typedef float floatx4 __attribute__((ext_vector_type(4)));

// ws layout (floats): ws[b*65 + j] = column-j partial sum from block b (j<64)
//                     ws[b*65 + 64] = sum-of-squares partial from block b
// No zero-init needed: every slot we read is unconditionally written by kernel A.

__global__ __launch_bounds__(256) void cross_partial_kernel(
    const float* __restrict__ cross, float* __restrict__ ws) {
    // 64 blocks x 256 threads; block b reduces rows [b*64, b*64+64) of V (4096x64)
    const int j  = threadIdx.x & 63;   // column 0..63
    const int rl = threadIdx.x >> 6;   // wave id 0..3
    const int row0 = blockIdx.x * 64;

    float s = 0.f, q = 0.f;
#pragma unroll
    for (int i = 0; i < 16; ++i) {
        // wave rl reads rows [row0+rl*16, row0+rl*16+16): 256B coalesced per row
        const float v = cross[(size_t)(row0 + rl * 16 + i) * K + j];
        s += v;
        q += v * v;
    }

    __shared__ float ls[256];
    __shared__ float lq[256];
    ls[threadIdx.x] = s;
    lq[threadIdx.x] = q;
    __syncthreads();

    if (threadIdx.x < 64) {
        const float cs = ls[j] + ls[j + 64] + ls[j + 128] + ls[j + 192];
        ws[blockIdx.x * 65 + j] = cs;

        float cq = lq[j] + lq[j + 64] + lq[j + 128] + lq[j + 192];
#pragma unroll
        for (int off = 32; off; off >>= 1) cq += __shfl_down(cq, off, 64);
        if (j == 0) ws[blockIdx.x * 65 + 64] = cq;
    }
}

__global__ __launch_bounds__(256) void gemv_sigmoid_kernel(
    const float* __restrict__ x, const float* __restrict__ w,
    const float* __restrict__ bias, const float* __restrict__ ws,
    float* __restrict__ out) {
    const int row = blockIdx.x;   // one block per output row
    const int tid = threadIdx.x;

    // Prologue (wave 0): fold the 64 cross partials into the scalar cross_sum.
    // 16KB of L2-hot reads; overlaps with the main loop's HBM loads in waves 1-3.
    __shared__ float s_cross;
    if (tid < 64) {
        float cs = 0.f;
#pragma unroll 8
        for (int b = 0; b < 64; ++b) cs += ws[b * 65 + tid];
        // val = cs_j^2 + diag-partial_j; total over j gives colsum.colsum + sum(V*V)
        float val = cs * cs + ws[tid * 65 + 64];
#pragma unroll
        for (int off = 32; off; off >>= 1) val += __shfl_down(val, off, 64);
        if (tid == 0) s_cross = 0.5f * val;
    }

    // Main dot product: 4096 floats per row, float4-vectorized, coalesced.
    // x is streamed exactly once -> non-temporal; w is reused by all 4096 blocks.
    const floatx4* __restrict__ xr = (const floatx4*)(x + (size_t)row * FEAS);
    const floatx4* __restrict__ wv = (const floatx4*)w;
    float acc = 0.f;
#pragma unroll
    for (int i = 0; i < 4; ++i) {
        const int idx = tid + i * 256;
        const floatx4 a = __builtin_nontemporal_load(&xr[idx]);
        const floatx4 b = wv[idx];
        acc += a.x * b.x + a.y * b.y + a.z * b.z + a.w * b.w;
    }

    // Wave reduce then cross-wave reduce via LDS.
#pragma unroll
    for (int off = 32; off; off >>= 1) acc += __shfl_down(acc, off, 64);
    __shared__ float partial[4];
    if ((tid & 63) == 0) partial[tid >> 6] = acc;
    __syncthreads();

    if (tid == 0) {
        const float y = partial[0] + partial[1] + partial[2] + partial[3]
                        + bias[0] + s_cross;
        out[row] = 1.0f / (1.0f + expf(-y));
    }
}

extern "C" void kernel_launch(void* const* d_in, const int* in_sizes, int n_in,
                              void* d_out, int out_size, void* d_ws, size_t ws_size,
                              hipStream_t stream) {
    const float* x     = (const float*)d_in[0];  // (4096, 4096)
    const float* cross = (const float*)d_in[1];  // (4096, 1, 64)
    const float* w     = (const float*)d_in[2];  // (1, 4096)
    const float* b     = (const float*)d_in[3];  // (1,)
    float* out = (float*)d_out;                  // (4096, 1)
    float* ws  = (float*)d_ws;

    cross_partial_kernel<<<NBLK, 256, 0, stream>>>(cross, ws);
    gemv_sigmoid_kernel<<<BATCH, 256, 0, stream>>>(x, w, b, ws, out);
}

// Round 4
// 101.702 us; speedup vs baseline: 1.0558x; 1.0558x over previous
//
#include <hip/hip_runtime.h>
#include <math.h>

#define FEAS 4096
#define K 64
#define BATCH 4096
#define NBLK 64

typedef float floatx4 __attribute__((ext_vector_type(4)));

// ws layout (floats):
//   ws[b*65 + j]  : column-j partial sum from block b   (j<64)
//   ws[b*65 + 64] : sum-of-squares partial from block b
//   ws[4160]      : FINAL scalar cross_sum (written by last-finishing block)
//   ws[4161]      : ticket counter (uint, zeroed by memset below)
#define FINAL_IDX 4160
#define CTR_IDX   4161

__global__ __launch_bounds__(256) void cross_reduce_kernel(
    const float* __restrict__ cross, float* __restrict__ ws) {
    // 64 blocks x 256 threads; block b reduces rows [b*64, b*64+64) of V (4096x64)
    const int j  = threadIdx.x & 63;   // column 0..63
    const int rl = threadIdx.x >> 6;   // wave id 0..3
    const int row0 = blockIdx.x * 64;

    float s = 0.f, q = 0.f;
#pragma unroll
    for (int i = 0; i < 16; ++i) {
        const float v = cross[(size_t)(row0 + rl * 16 + i) * K + j];
        s += v;
        q += v * v;
    }

    __shared__ float ls[256];
    __shared__ float lq[256];
    ls[threadIdx.x] = s;
    lq[threadIdx.x] = q;
    __syncthreads();

    __shared__ bool amLast;
    if (threadIdx.x < 64) {
        const float cs = ls[j] + ls[j + 64] + ls[j + 128] + ls[j + 192];
        ws[blockIdx.x * 65 + j] = cs;

        float cq = lq[j] + lq[j + 64] + lq[j + 128] + lq[j + 192];
#pragma unroll
        for (int off = 32; off; off >>= 1) cq += __shfl_down(cq, off, 64);
        if (j == 0) {
            ws[blockIdx.x * 65 + 64] = cq;
            __threadfence();  // release our partials (device scope)
            unsigned old = atomicAdd((unsigned*)&ws[CTR_IDX], 1u);
            amLast = (old == NBLK - 1);
        }
    }
    __syncthreads();

    // Last-finishing block folds all 64 partials into the final scalar.
    if (amLast && threadIdx.x < 64) {
        __threadfence();  // acquire all other blocks' partials
        float csum = 0.f;
#pragma unroll 8
        for (int b = 0; b < NBLK; ++b) csum += ws[b * 65 + threadIdx.x];
        float val = csum * csum + ws[threadIdx.x * 65 + 64];
#pragma unroll
        for (int off = 32; off; off >>= 1) val += __shfl_down(val, off, 64);
        if (threadIdx.x == 0) ws[FINAL_IDX] = 0.5f * val;
    }
}

__global__ __launch_bounds__(256) void gemv_sigmoid_kernel(
    const float* __restrict__ x, const float* __restrict__ w,
    const float* __restrict__ bias, const float* __restrict__ ws,
    float* __restrict__ out) {
    const int row = blockIdx.x;   // one block per output row
    const int tid = threadIdx.x;

    // Prefetch the scalar cross_sum + bias early; used only in the epilogue.
    const float cross_sum = ws[FINAL_IDX];
    const float b0 = bias[0];

    // Main dot product: 4096 floats per row, float4-vectorized, coalesced.
    const floatx4* __restrict__ xr = (const floatx4*)(x + (size_t)row * FEAS);
    const floatx4* __restrict__ wv = (const floatx4*)w;
    float acc = 0.f;
#pragma unroll
    for (int i = 0; i < 4; ++i) {
        const int idx = tid + i * 256;
        const floatx4 a = xr[idx];
        const floatx4 b = wv[idx];
        acc += a.x * b.x + a.y * b.y + a.z * b.z + a.w * b.w;
    }

    // Wave reduce then cross-wave reduce via LDS.
#pragma unroll
    for (int off = 32; off; off >>= 1) acc += __shfl_down(acc, off, 64);
    __shared__ float partial[4];
    if ((tid & 63) == 0) partial[tid >> 6] = acc;
    __syncthreads();

    if (tid == 0) {
        const float y = partial[0] + partial[1] + partial[2] + partial[3]
                        + b0 + cross_sum;
        out[row] = 1.0f / (1.0f + expf(-y));
    }
}

extern "C" void kernel_launch(void* const* d_in, const int* in_sizes, int n_in,
                              void* d_out, int out_size, void* d_ws, size_t ws_size,
                              hipStream_t stream) {
    const float* x     = (const float*)d_in[0];  // (4096, 4096)
    const float* cross = (const float*)d_in[1];  // (4096, 1, 64)
    const float* w     = (const float*)d_in[2];  // (1, 4096)
    const float* b     = (const float*)d_in[3];  // (1,)
    float* out = (float*)d_out;                  // (4096, 1)
    float* ws  = (float*)d_ws;

    // Zero only the 4-byte ticket counter (ws is re-poisoned to 0xAA each run).
    hipMemsetAsync(ws + CTR_IDX, 0, sizeof(unsigned), stream);

    cross_reduce_kernel<<<NBLK, 256, 0, stream>>>(cross, ws);
    gemv_sigmoid_kernel<<<BATCH, 256, 0, stream>>>(x, w, b, ws, out);
}